// Round 1
// baseline (930.111 us; speedup 1.0000x reference)
//
#include <hip/hip_runtime.h>
#include <hip/hip_bf16.h>

// Problem constants
#define B_   2
#define C_   256
#define T_   4096
#define GRP  32
#define CPG  8            // channels per group
#define NH   4
#define CH   64           // channels per head
#define K3C  768          // 3*C

// ---------------------------------------------------------------------------
// Kernel 1: GroupNorm.  One block per (batch, group).  8*4096 = 32768 elems.
// ---------------------------------------------------------------------------
__global__ __launch_bounds__(256) void gn_kernel(
    const float* __restrict__ x, const float* __restrict__ w,
    const float* __restrict__ b, float* __restrict__ xn) {
    int bg = blockIdx.x;               // 0..63
    int batch = bg / GRP, g = bg % GRP;
    const float* xp = x + ((size_t)batch * C_ + (size_t)g * CPG) * T_;
    float* op = xn + ((size_t)batch * C_ + (size_t)g * CPG) * T_;
    int tid = threadIdx.x;

    float s = 0.f, s2 = 0.f;
    for (int i = tid; i < CPG * T_; i += 256) {
        float v = xp[i];
        s += v; s2 += v * v;
    }
    // wave reduction (64 lanes)
    for (int off = 32; off > 0; off >>= 1) {
        s  += __shfl_down(s,  off);
        s2 += __shfl_down(s2, off);
    }
    __shared__ float rs[4], rs2[4];
    int wid = tid >> 6;
    if ((tid & 63) == 0) { rs[wid] = s; rs2[wid] = s2; }
    __syncthreads();
    if (tid == 0) {
        float a = 0.f, a2 = 0.f;
        for (int i = 0; i < 4; i++) { a += rs[i]; a2 += rs2[i]; }
        float inv_n = 1.f / (float)(CPG * T_);
        rs[0]  = a * inv_n;            // mean
        rs2[0] = a2 * inv_n;           // mean of squares
    }
    __syncthreads();
    float mean = rs[0];
    float var  = rs2[0] - mean * mean;
    float inv  = rsqrtf(var + 1e-5f);
    for (int i = tid; i < CPG * T_; i += 256) {
        int c = g * CPG + i / T_;
        op[i] = (xp[i] - mean) * inv * w[c] + b[c];
    }
}

// ---------------------------------------------------------------------------
// Kernel 2/4: fp32 GEMM  Y[b,o,t] = bias[o] + sum_c W[o,c] * X[b,c,t] (+resid)
// grid = (T/64, OCH/64, B), block = 256.  64x64 tile, K-chunk 16.
// ---------------------------------------------------------------------------
__global__ __launch_bounds__(256) void gemm_kernel(
    const float* __restrict__ W, const float* __restrict__ bias,
    const float* __restrict__ X, float* __restrict__ Y,
    const float* __restrict__ resid, int OCH) {
    const int K = C_;
    int tb = blockIdx.x * 64;
    int ob = blockIdx.y * 64;
    int batch = blockIdx.z;
    const float* Xb = X + (size_t)batch * K * T_;

    __shared__ float Ws[16][68];   // [k][o], padded
    __shared__ float Xs[16][64];   // [k][t]

    int tid = threadIdx.x;
    int tx = tid & 15;             // t-subtile
    int ty = tid >> 4;             // o-subtile

    float acc[4][4];
#pragma unroll
    for (int i = 0; i < 4; i++)
#pragma unroll
        for (int j = 0; j < 4; j++) acc[i][j] = 0.f;

    for (int k0 = 0; k0 < K; k0 += 16) {
        {
            int ci = tid & 15, oi0 = tid >> 4;
            for (int oi = oi0; oi < 64; oi += 16)
                Ws[ci][oi] = W[(size_t)(ob + oi) * K + k0 + ci];
            int tt = tid & 63, kk0 = tid >> 6;
            for (int kk = kk0; kk < 16; kk += 4)
                Xs[kk][tt] = Xb[(size_t)(k0 + kk) * T_ + tb + tt];
        }
        __syncthreads();
#pragma unroll
        for (int kk = 0; kk < 16; kk++) {
            float wf[4], xf[4];
#pragma unroll
            for (int i = 0; i < 4; i++) wf[i] = Ws[kk][ty * 4 + i];
#pragma unroll
            for (int j = 0; j < 4; j++) xf[j] = Xs[kk][tx * 4 + j];
#pragma unroll
            for (int i = 0; i < 4; i++)
#pragma unroll
                for (int j = 0; j < 4; j++) acc[i][j] += wf[i] * xf[j];
        }
        __syncthreads();
    }

#pragma unroll
    for (int i = 0; i < 4; i++) {
        int o = ob + ty * 4 + i;
        size_t base = ((size_t)batch * OCH + o) * T_ + tb + tx * 4;
        float bv = bias[o];
#pragma unroll
        for (int j = 0; j < 4; j++) {
            float v = acc[i][j] + bv;
            if (resid) v += resid[base + j];
            Y[base + j] = v;
        }
    }
}

// ---------------------------------------------------------------------------
// Kernel 3: flash attention.  grid = (T/64, B*NH), block = 256.
// qkv layout (B, 768, T); head h of batch b: q rows [h*192, +64), k +64, v +128.
// scale^2 = ch^-0.5 = 0.125
// ---------------------------------------------------------------------------
__global__ __launch_bounds__(256) void attn_kernel(
    const float* __restrict__ qkv, float* __restrict__ a) {
    int bh = blockIdx.y;                 // 0..7
    int batch = bh >> 2, h = bh & 3;
    int qt = blockIdx.x * 64;
    const float* qp = qkv + ((size_t)batch * K3C + (size_t)h * 3 * CH) * T_;
    const float* kp = qp + (size_t)CH * T_;
    const float* vp = qp + (size_t)2 * CH * T_;

    __shared__ float Qs[64][64];    // [c][t]
    __shared__ float Ks[64][64];    // [c][s]
    __shared__ float Vs[64][68];    // [s][c] padded
    __shared__ float Ps[64][64];    // [s][t]
    __shared__ float red[4][64];
    __shared__ float rowm[64], rowl[64];

    int tid = threadIdx.x;
    int t   = tid & 63;             // t within tile (also s-col for loads)
    int grp = tid >> 6;             // wave id 0..3
    int sb  = grp * 16;             // S columns owned in QK^T phase
    int cb  = grp * 16;             // O channels owned in PV phase

    for (int c = grp; c < 64; c += 4)
        Qs[c][t] = qp[(size_t)c * T_ + qt + t];
    if (tid < 64) { rowm[tid] = -1e30f; rowl[tid] = 0.f; }

    float O[16];
#pragma unroll
    for (int i = 0; i < 16; i++) O[i] = 0.f;
    __syncthreads();

    for (int s0 = 0; s0 < T_; s0 += 64) {
        // stage K (as [c][s]) and V (transposed [s][c])
        for (int c = grp; c < 64; c += 4) {
            Ks[c][t] = kp[(size_t)c * T_ + s0 + t];
            Vs[t][c] = vp[(size_t)c * T_ + s0 + t];
        }
        __syncthreads();                                   // A

        // S[t][sb+j] = 0.125 * sum_c Q[c][t] K[c][sb+j]
        float S[16];
#pragma unroll
        for (int j = 0; j < 16; j++) S[j] = 0.f;
        for (int c = 0; c < 64; c++) {
            float q = Qs[c][t];
#pragma unroll
            for (int j = 0; j < 16; j++) S[j] += q * Ks[c][sb + j];
        }
        float mloc = -1e30f;
#pragma unroll
        for (int j = 0; j < 16; j++) {
            S[j] *= 0.125f;
            mloc = fmaxf(mloc, S[j]);
        }
        red[grp][t] = mloc;
        __syncthreads();                                   // B
        float mnew = fmaxf(fmaxf(red[0][t], red[1][t]),
                           fmaxf(red[2][t], red[3][t]));
        float mold = rowm[t];
        mnew = fmaxf(mnew, mold);
        float alpha = __expf(mold - mnew);
        float lloc = 0.f;
#pragma unroll
        for (int j = 0; j < 16; j++) {
            float p = __expf(S[j] - mnew);
            lloc += p;
            Ps[sb + j][t] = p;
        }
        __syncthreads();                                   // C
        red[grp][t] = lloc;
        if (grp == 0) rowm[t] = mnew;
        __syncthreads();                                   // D
        if (grp == 0) {
            float lsum = red[0][t] + red[1][t] + red[2][t] + red[3][t];
            rowl[t] = rowl[t] * alpha + lsum;
        }
        // rescale O and accumulate P·V
#pragma unroll
        for (int i = 0; i < 16; i++) O[i] *= alpha;
        for (int s = 0; s < 64; s++) {
            float pp = Ps[s][t];
#pragma unroll
            for (int i = 0; i < 16; i++) O[i] += pp * Vs[s][cb + i];
        }
        __syncthreads();                                   // E
    }

    float linv = 1.f / rowl[t];
#pragma unroll
    for (int i = 0; i < 16; i++) {
        size_t idx = ((size_t)batch * C_ + (size_t)(h * CH + cb + i)) * T_ + qt + t;
        a[idx] = O[i] * linv;
    }
}

// ---------------------------------------------------------------------------
extern "C" void kernel_launch(void* const* d_in, const int* in_sizes, int n_in,
                              void* d_out, int out_size, void* d_ws, size_t ws_size,
                              hipStream_t stream) {
    const float* x      = (const float*)d_in[0];
    const float* norm_w = (const float*)d_in[1];
    const float* norm_b = (const float*)d_in[2];
    const float* qkv_w  = (const float*)d_in[3];
    const float* qkv_b  = (const float*)d_in[4];
    const float* proj_w = (const float*)d_in[5];
    const float* proj_b = (const float*)d_in[6];
    float* out = (float*)d_out;

    float* xn  = (float*)d_ws;                       // B*C*T  = 2,097,152 f
    float* qkv = xn  + (size_t)B_ * C_ * T_;         // B*768*T = 6,291,456 f
    float* av  = qkv + (size_t)B_ * K3C * T_;        // B*C*T  = 2,097,152 f

    // 1. GroupNorm
    gn_kernel<<<dim3(B_ * GRP), dim3(256), 0, stream>>>(x, norm_w, norm_b, xn);

    // 2. QKV projection: (768x256) x (256x4096) per batch
    gemm_kernel<<<dim3(T_ / 64, K3C / 64, B_), dim3(256), 0, stream>>>(
        qkv_w, qkv_b, xn, qkv, nullptr, K3C);

    // 3. Attention
    attn_kernel<<<dim3(T_ / 64, B_ * NH), dim3(256), 0, stream>>>(qkv, av);

    // 4. Output projection + residual
    gemm_kernel<<<dim3(T_ / 64, C_ / 64, B_), dim3(256), 0, stream>>>(
        proj_w, proj_b, av, out, x, C_);
}

// Round 2
// 348.609 us; speedup vs baseline: 2.6681x; 2.6681x over previous
//
#include <hip/hip_runtime.h>

// Problem constants
#define B_   2
#define C_   256
#define T_   4096
#define GRP  32
#define CPG  8            // channels per group
#define NH   4
#define CH   64           // channels per head
#define K3C  768          // 3*C

typedef __attribute__((ext_vector_type(8))) short bf16x8;
typedef __attribute__((ext_vector_type(4))) float f32x4;

__device__ __forceinline__ unsigned short f2bf(float x) {
    unsigned u = __float_as_uint(x);
    u += 0x7fffu + ((u >> 16) & 1u);
    return (unsigned short)(u >> 16);
}
__device__ __forceinline__ unsigned pk2(float a, float b) {
    return (unsigned)f2bf(a) | ((unsigned)f2bf(b) << 16);
}

// ---------------------------------------------------------------------------
// Kernel 1: GroupNorm.  One block per (batch, group).
// ---------------------------------------------------------------------------
__global__ __launch_bounds__(256) void gn_kernel(
    const float* __restrict__ x, const float* __restrict__ w,
    const float* __restrict__ b, float* __restrict__ xn) {
    int bg = blockIdx.x;
    int batch = bg / GRP, g = bg % GRP;
    const float* xp = x + ((size_t)batch * C_ + (size_t)g * CPG) * T_;
    float* op = xn + ((size_t)batch * C_ + (size_t)g * CPG) * T_;
    int tid = threadIdx.x;

    float s = 0.f, s2 = 0.f;
    for (int i = tid; i < CPG * T_; i += 256) {
        float v = xp[i];
        s += v; s2 += v * v;
    }
    for (int off = 32; off > 0; off >>= 1) {
        s  += __shfl_down(s,  off);
        s2 += __shfl_down(s2, off);
    }
    __shared__ float rs[4], rs2[4];
    int wid = tid >> 6;
    if ((tid & 63) == 0) { rs[wid] = s; rs2[wid] = s2; }
    __syncthreads();
    if (tid == 0) {
        float a = 0.f, a2 = 0.f;
        for (int i = 0; i < 4; i++) { a += rs[i]; a2 += rs2[i]; }
        float inv_n = 1.f / (float)(CPG * T_);
        rs[0]  = a * inv_n;
        rs2[0] = a2 * inv_n;
    }
    __syncthreads();
    float mean = rs[0];
    float var  = rs2[0] - mean * mean;
    float inv  = rsqrtf(var + 1e-5f);
    for (int i = tid; i < CPG * T_; i += 256) {
        int c = g * CPG + i / T_;
        op[i] = (xp[i] - mean) * inv * w[c] + b[c];
    }
}

// ---------------------------------------------------------------------------
// Kernel 2/4: fp32 GEMM  Y[b,o,t] = bias[o] + sum_c W[o,c] * X[b,c,t] (+resid)
// ---------------------------------------------------------------------------
__global__ __launch_bounds__(256) void gemm_kernel(
    const float* __restrict__ W, const float* __restrict__ bias,
    const float* __restrict__ X, float* __restrict__ Y,
    const float* __restrict__ resid, int OCH) {
    const int K = C_;
    int tb = blockIdx.x * 64;
    int ob = blockIdx.y * 64;
    int batch = blockIdx.z;
    const float* Xb = X + (size_t)batch * K * T_;

    __shared__ float Ws[16][68];
    __shared__ float Xs[16][64];

    int tid = threadIdx.x;
    int tx = tid & 15;
    int ty = tid >> 4;

    float acc[4][4];
#pragma unroll
    for (int i = 0; i < 4; i++)
#pragma unroll
        for (int j = 0; j < 4; j++) acc[i][j] = 0.f;

    for (int k0 = 0; k0 < K; k0 += 16) {
        {
            int ci = tid & 15, oi0 = tid >> 4;
            for (int oi = oi0; oi < 64; oi += 16)
                Ws[ci][oi] = W[(size_t)(ob + oi) * K + k0 + ci];
            int tt = tid & 63, kk0 = tid >> 6;
            for (int kk = kk0; kk < 16; kk += 4)
                Xs[kk][tt] = Xb[(size_t)(k0 + kk) * T_ + tb + tt];
        }
        __syncthreads();
#pragma unroll
        for (int kk = 0; kk < 16; kk++) {
            float wf[4], xf[4];
#pragma unroll
            for (int i = 0; i < 4; i++) wf[i] = Ws[kk][ty * 4 + i];
#pragma unroll
            for (int j = 0; j < 4; j++) xf[j] = Xs[kk][tx * 4 + j];
#pragma unroll
            for (int i = 0; i < 4; i++)
#pragma unroll
                for (int j = 0; j < 4; j++) acc[i][j] += wf[i] * xf[j];
        }
        __syncthreads();
    }

#pragma unroll
    for (int i = 0; i < 4; i++) {
        int o = ob + ty * 4 + i;
        size_t base = ((size_t)batch * OCH + o) * T_ + tb + tx * 4;
        float bv = bias[o];
#pragma unroll
        for (int j = 0; j < 4; j++) {
            float v = acc[i][j] + bv;
            if (resid) v += resid[base + j];
            Y[base + j] = v;
        }
    }
}

// ---------------------------------------------------------------------------
// Kernel 3: MFMA flash attention, S^T orientation.
// grid = (T/64, B*NH), block = 256 (4 waves).  Wave w owns t-block w (16 t).
// S^T = K^T(Q*0.125): M=s, N=t, K=c.   O^T = V.P^T: M=c, N=t, K=s.
// Per-lane: one t = 16w + (lane&15); m/l/alpha are lane scalars.
// ---------------------------------------------------------------------------
__global__ __launch_bounds__(256) void attn_kernel(
    const float* __restrict__ qkv, float* __restrict__ a_out) {
    int bh = blockIdx.y;
    int batch = bh >> 2, h = bh & 3;
    int qt = blockIdx.x * 64;
    const float* qp = qkv + ((size_t)batch * K3C + (size_t)h * 3 * CH) * T_;
    const float* kp = qp + (size_t)CH * T_;
    const float* vp = qp + (size_t)2 * CH * T_;

    __shared__ unsigned short Kt[64][72];   // [s][c] bf16 (also Q staging [t][c])
    __shared__ unsigned short Vt[64][72];   // [c][s] bf16
    __shared__ unsigned short Ps[64][72];   // [t][s] bf16

    int tid = threadIdx.x;
    int l   = tid & 15;            // intra-frag lane
    int q   = (tid >> 4) & 3;      // quad
    int w   = tid >> 6;            // wave = t-block
    int l6  = tid & 63;

    // ---- stage Q (pre-scaled) transposed into Kt buffer: Qs[t][c] ----
#pragma unroll
    for (int p = 0; p < 2; ++p) {
        int c0 = 8 * (w + 4 * p);
        const float* src = qp + (size_t)c0 * T_ + qt + l6;
        float v0[8];
#pragma unroll
        for (int i = 0; i < 8; ++i) v0[i] = src[(size_t)i * T_] * 0.125f;
        uint4 wv;
        wv.x = pk2(v0[0], v0[1]); wv.y = pk2(v0[2], v0[3]);
        wv.z = pk2(v0[4], v0[5]); wv.w = pk2(v0[6], v0[7]);
        *(uint4*)&Kt[l6][c0] = wv;
    }
    __syncthreads();
    bf16x8 qf[2];
#pragma unroll
    for (int kk = 0; kk < 2; ++kk)
        qf[kk] = *(const bf16x8*)&Kt[16 * w + l][32 * kk + 8 * q];
    __syncthreads();

    f32x4 O[4];
#pragma unroll
    for (int mf = 0; mf < 4; ++mf) O[mf] = (f32x4){0.f, 0.f, 0.f, 0.f};
    float m_run = -1e30f, l_run = 0.f;

    for (int s0 = 0; s0 < T_; s0 += 64) {
        // ---- stage K transposed: Kt[s][c] ----
#pragma unroll
        for (int p = 0; p < 2; ++p) {
            int c0 = 8 * (w + 4 * p);
            const float* src = kp + (size_t)c0 * T_ + s0 + l6;
            float v0[8];
#pragma unroll
            for (int i = 0; i < 8; ++i) v0[i] = src[(size_t)i * T_];
            uint4 wv;
            wv.x = pk2(v0[0], v0[1]); wv.y = pk2(v0[2], v0[3]);
            wv.z = pk2(v0[4], v0[5]); wv.w = pk2(v0[6], v0[7]);
            *(uint4*)&Kt[l6][c0] = wv;
        }
        // ---- stage V direct: Vt[c][s] ----
        {
            int c = tid >> 3;
            int s8 = (tid & 7) * 8;
#pragma unroll
            for (int p = 0; p < 2; ++p, c += 32) {
                const float* src = vp + (size_t)c * T_ + s0 + s8;
                float4 f0 = *(const float4*)src;
                float4 f1 = *(const float4*)(src + 4);
                uint4 wv;
                wv.x = pk2(f0.x, f0.y); wv.y = pk2(f0.z, f0.w);
                wv.z = pk2(f1.x, f1.y); wv.w = pk2(f1.z, f1.w);
                *(uint4*)&Vt[c][s8] = wv;
            }
        }
        __syncthreads();

        // ---- QK^T: S^T frags, rows s=16sf+4q+r, col t=16w+l ----
        f32x4 S[4];
#pragma unroll
        for (int sf = 0; sf < 4; ++sf) {
            f32x4 acc = (f32x4){0.f, 0.f, 0.f, 0.f};
#pragma unroll
            for (int kk = 0; kk < 2; ++kk) {
                bf16x8 ka = *(const bf16x8*)&Kt[16 * sf + l][32 * kk + 8 * q];
                acc = __builtin_amdgcn_mfma_f32_16x16x32_bf16(ka, qf[kk], acc, 0, 0, 0);
            }
            S[sf] = acc;
        }

        // ---- online softmax (per-lane scalar state; reduce over quads) ----
        float mx = -1e30f;
#pragma unroll
        for (int sf = 0; sf < 4; ++sf)
#pragma unroll
            for (int r = 0; r < 4; ++r) mx = fmaxf(mx, S[sf][r]);
        mx = fmaxf(mx, __shfl_xor(mx, 16));
        mx = fmaxf(mx, __shfl_xor(mx, 32));
        float m_new = fmaxf(m_run, mx);
        float alpha = __expf(m_run - m_new);
        float lloc = 0.f;
#pragma unroll
        for (int sf = 0; sf < 4; ++sf) {
            float p0 = __expf(S[sf][0] - m_new);
            float p1 = __expf(S[sf][1] - m_new);
            float p2 = __expf(S[sf][2] - m_new);
            float p3 = __expf(S[sf][3] - m_new);
            lloc += (p0 + p1) + (p2 + p3);
            uint2 u; u.x = pk2(p0, p1); u.y = pk2(p2, p3);
            *(uint2*)&Ps[16 * w + l][16 * sf + 4 * q] = u;   // own rows: no barrier
        }
        lloc += __shfl_xor(lloc, 16);
        lloc += __shfl_xor(lloc, 32);
        l_run = l_run * alpha + lloc;
        m_run = m_new;
#pragma unroll
        for (int mf = 0; mf < 4; ++mf)
#pragma unroll
            for (int r = 0; r < 4; ++r) O[mf][r] *= alpha;

        // ---- PV: O^T[c][t], A=V[c][s], B=P^T[s][t] (intra-wave rows) ----
#pragma unroll
        for (int kk = 0; kk < 2; ++kk) {
            bf16x8 pb = *(const bf16x8*)&Ps[16 * w + l][32 * kk + 8 * q];
#pragma unroll
            for (int mf = 0; mf < 4; ++mf) {
                bf16x8 va = *(const bf16x8*)&Vt[16 * mf + l][32 * kk + 8 * q];
                O[mf] = __builtin_amdgcn_mfma_f32_16x16x32_bf16(va, pb, O[mf], 0, 0, 0);
            }
        }
        __syncthreads();
    }

    float inv = 1.f / l_run;
    int t = qt + 16 * w + l;
#pragma unroll
    for (int mf = 0; mf < 4; ++mf)
#pragma unroll
        for (int r = 0; r < 4; ++r) {
            int c = h * CH + 16 * mf + 4 * q + r;
            a_out[((size_t)batch * C_ + c) * T_ + t] = O[mf][r] * inv;
        }
}

// ---------------------------------------------------------------------------
extern "C" void kernel_launch(void* const* d_in, const int* in_sizes, int n_in,
                              void* d_out, int out_size, void* d_ws, size_t ws_size,
                              hipStream_t stream) {
    const float* x      = (const float*)d_in[0];
    const float* norm_w = (const float*)d_in[1];
    const float* norm_b = (const float*)d_in[2];
    const float* qkv_w  = (const float*)d_in[3];
    const float* qkv_b  = (const float*)d_in[4];
    const float* proj_w = (const float*)d_in[5];
    const float* proj_b = (const float*)d_in[6];
    float* out = (float*)d_out;

    float* xn  = (float*)d_ws;
    float* qkv = xn  + (size_t)B_ * C_ * T_;
    float* av  = qkv + (size_t)B_ * K3C * T_;

    gn_kernel<<<dim3(B_ * GRP), dim3(256), 0, stream>>>(x, norm_w, norm_b, xn);

    gemm_kernel<<<dim3(T_ / 64, K3C / 64, B_), dim3(256), 0, stream>>>(
        qkv_w, qkv_b, xn, qkv, nullptr, K3C);

    attn_kernel<<<dim3(T_ / 64, B_ * NH), dim3(256), 0, stream>>>(qkv, av);

    gemm_kernel<<<dim3(T_ / 64, C_ / 64, B_), dim3(256), 0, stream>>>(
        proj_w, proj_b, av, out, x, C_);
}